// Round 4
// baseline (226.751 us; speedup 1.0000x reference)
//
#include <hip/hip_runtime.h>
#include <hip/hip_bf16.h>
#include <math.h>

#define T_ 4
#define B_ 8
#define C_ 256
#define HID_ 1024
#define E_ 8
#define K_ 2
#define HW_ 196
#define M_ 784            // T*HW rows per (b,expert) pair, r = hw*4 + t
#define NPAIR_ 16         // B*K active pairs
#define EPS_ 1e-5f

typedef __attribute__((ext_vector_type(8))) short bf16x8;
typedef __attribute__((ext_vector_type(8))) unsigned short u16x8;
typedef __attribute__((ext_vector_type(4))) float f32x4;

__device__ inline unsigned short f2bf(float f){
  union { float f; unsigned u; } v; v.f = f;
  unsigned u = v.u;
  unsigned r = u + 0x7FFFu + ((u >> 16) & 1u);   // RNE
  return (unsigned short)(r >> 16);
}
__device__ inline float bf2f(unsigned short h){
  union { unsigned u; float f; } v; v.u = ((unsigned)h) << 16;
  return v.f;
}

// ---- split f32 weights into bf16 hi/lo pair (exact to ~2^-17 relative) ----
__global__ __launch_bounds__(256) void wconv_kernel(const float* __restrict__ w,
    unsigned short* __restrict__ hi, unsigned short* __restrict__ lo, int n){
  int i = blockIdx.x * 256 + threadIdx.x;
  if (i >= n) return;
  float f = w[i];
  unsigned short h = f2bf(f);
  hi[i] = h;
  lo[i] = f2bf(f - bf2f(h));
}

// ---- xbar[b,c] = mean over (t,hw) of x ----
__global__ __launch_bounds__(64) void xbar_kernel(const float* __restrict__ x,
                                                  float* __restrict__ xbar){
  int bc = blockIdx.x;           // b*C + c
  int l = threadIdx.x;
  float s = 0.f;
  for (int t = 0; t < T_; t++){
    const float* p = x + ((size_t)(t * B_ * C_) + bc) * HW_;
    for (int i = l; i < HW_; i += 64) s += p[i];
  }
  for (int off = 32; off > 0; off >>= 1) s += __shfl_down(s, off, 64);
  if (l == 0) xbar[bc] = s * (1.0f / (T_ * HW_));
}

// ---- router: logits -> softmax -> top2 -> (expert id, weight) per pair ----
__global__ __launch_bounds__(64) void router_kernel(const float* __restrict__ xbar,
    const float* __restrict__ rw, const float* __restrict__ rb,
    const float* __restrict__ rg, const float* __restrict__ rbb,
    const float* __restrict__ rm, const float* __restrict__ rv,
    int* __restrict__ sel_e, float* __restrict__ sel_w){
  __shared__ float lg[64];
  const int tid = threadIdx.x;
  const int b = tid >> 3, e = tid & 7;
  float dot = 0.f;
  for (int c = 0; c < C_; c++) dot += xbar[b * C_ + c] * rw[e * C_ + c];
  dot += rb[e];
  float sc = rg[e] / sqrtf(rv[e] + EPS_);
  lg[tid] = (dot - rm[e]) * sc + rbb[e];
  __syncthreads();
  if (e == 0){
    float l[E_], mx = -1e30f;
    for (int i = 0; i < E_; i++){ l[i] = lg[b * 8 + i]; mx = fmaxf(mx, l[i]); }
    float p[E_];
    for (int i = 0; i < E_; i++) p[i] = expf(l[i] - mx);
    int i1 = 0;
    for (int i = 1; i < E_; i++) if (p[i] > p[i1]) i1 = i;       // first index on ties
    int i2 = (i1 == 0) ? 1 : 0;
    for (int i = 0; i < E_; i++) if (i != i1 && p[i] > p[i2]) i2 = i;
    float denom = p[i1] + p[i2];
    sel_e[b * 2]     = i1; sel_w[b * 2]     = p[i1] / denom;
    sel_e[b * 2 + 1] = i2; sel_w[b * 2 + 1] = p[i2] / denom;
  }
}

// ---- LIF1: x -> s1 spikes (bf16 0/1), layout s1[pair][hw*4+t][c] ----
__global__ __launch_bounds__(256) void lif1_kernel(const float* __restrict__ x,
    const int* __restrict__ sel_e, const float* __restrict__ taus,
    unsigned short* __restrict__ s1){
  const int hw = blockIdx.x;      // 0..195
  const int pair = blockIdx.y;    // 0..15
  const int c = threadIdx.x;      // 0..255
  const int b = pair >> 1;
  const float tau = taus[sel_e[pair]];
  float v = 0.f;
  #pragma unroll
  for (int t = 0; t < T_; t++){
    float xv = x[((size_t)(t * B_ + b) * C_ + c) * HW_ + hw];
    float h = v + (xv - v) / tau;                 // same formula as reference
    float s = (h >= 1.0f) ? 1.0f : 0.0f;
    v = h * (1.0f - s);                           // hard reset
    s1[((size_t)pair * M_ + hw * 4 + t) * C_ + c] =
        (s > 0.5f) ? (unsigned short)0x3F80 : (unsigned short)0;
  }
}

// ---- GEMM1 (s1 @ w1^T) + bias + BN1 + LIF2 -> s2 spikes ----
// tile 64x64, K=256 in steps of 32, split-weight hi/lo double-MFMA.
__global__ __launch_bounds__(256) void g1_kernel(
    const unsigned short* __restrict__ s1,
    const unsigned short* __restrict__ w1h, const unsigned short* __restrict__ w1l,
    const float* __restrict__ fc1_b,
    const float* __restrict__ bn1_g, const float* __restrict__ bn1_b,
    const float* __restrict__ bn1_m, const float* __restrict__ bn1_v,
    const int* __restrict__ sel_e, const float* __restrict__ taus,
    unsigned short* __restrict__ s2)
{
  __shared__ __align__(16) unsigned short lA[64 * 40];   // +8 pad: read-conflict-free
  __shared__ __align__(16) unsigned short lBh[64 * 40];
  __shared__ __align__(16) unsigned short lBl[64 * 40];
  const int nt = blockIdx.x, mt = blockIdx.y, pair = blockIdx.z;
  const int e = sel_e[pair];
  const int m0 = mt * 64, n0 = nt * 64;
  const int tid = threadIdx.x;
  const int row = tid >> 2, seg = tid & 3;
  const int lane = tid & 63, wv = tid >> 6;
  const int koff = (lane >> 4) * 8;
  const unsigned short* s1p = s1 + (size_t)pair * (M_ * C_);
  const unsigned short* bhp = w1h + ((size_t)e * HID_ + n0 + row) * C_ + seg * 8;
  const unsigned short* blp = w1l + ((size_t)e * HID_ + n0 + row) * C_ + seg * 8;
  f32x4 acc[4] = {};
  for (int kk = 0; kk < C_; kk += 32){
    int r = m0 + row;
    u16x8 av = {};
    if (r < M_) av = *(const u16x8*)(s1p + (size_t)r * C_ + kk + seg * 8);
    *(u16x8*)(lA  + row * 40 + seg * 8) = av;
    *(u16x8*)(lBh + row * 40 + seg * 8) = *(const u16x8*)(bhp + kk);
    *(u16x8*)(lBl + row * 40 + seg * 8) = *(const u16x8*)(blp + kk);
    __syncthreads();
    bf16x8 a = *(const bf16x8*)(lA + (wv * 16 + (lane & 15)) * 40 + koff);
    #pragma unroll
    for (int cb = 0; cb < 4; cb++){
      bf16x8 bh = *(const bf16x8*)(lBh + (cb * 16 + (lane & 15)) * 40 + koff);
      bf16x8 bl = *(const bf16x8*)(lBl + (cb * 16 + (lane & 15)) * 40 + koff);
      acc[cb] = __builtin_amdgcn_mfma_f32_16x16x32_bf16(a, bh, acc[cb], 0, 0, 0);
      acc[cb] = __builtin_amdgcn_mfma_f32_16x16x32_bf16(a, bl, acc[cb], 0, 0, 0);
    }
    __syncthreads();
  }
  // epilogue: lane holds all 4 timesteps (regs) of one (hw, col) -> LIF in-register
  const float tau = taus[e];
  const int rbase = m0 + wv * 16 + ((lane >> 4) << 2);
  if (rbase < M_){
    #pragma unroll
    for (int cb = 0; cb < 4; cb++){
      int col = n0 + cb * 16 + (lane & 15);
      int pi = e * HID_ + col;
      float sc = bn1_g[pi] / sqrtf(bn1_v[pi] + EPS_);
      float mm = bn1_m[pi], bb = bn1_b[pi], cbias = fc1_b[pi];
      float v = 0.f;
      #pragma unroll
      for (int t = 0; t < 4; t++){
        float z = acc[cb][t] + cbias;
        float hin = (z - mm) * sc + bb;
        float h = v + (hin - v) / tau;
        float s = (h >= 1.0f) ? 1.0f : 0.0f;
        v = h * (1.0f - s);
        s2[((size_t)pair * M_ + rbase + t) * HID_ + col] =
            (s > 0.5f) ? (unsigned short)0x3F80 : (unsigned short)0;
      }
    }
  }
}

// ---- GEMM2 (s2 @ w2^T) + bias + BN2, both slots, + x, write final out ----
__global__ __launch_bounds__(256) void g2_kernel(
    const unsigned short* __restrict__ s2,
    const unsigned short* __restrict__ w2h, const unsigned short* __restrict__ w2l,
    const float* __restrict__ fc2_b,
    const float* __restrict__ bn2_g, const float* __restrict__ bn2_b,
    const float* __restrict__ bn2_m, const float* __restrict__ bn2_v,
    const int* __restrict__ sel_e, const float* __restrict__ sel_w,
    const float* __restrict__ x, float* __restrict__ out)
{
  __shared__ __align__(16) unsigned short lA[64 * 40];
  __shared__ __align__(16) unsigned short lBh[64 * 40];
  __shared__ __align__(16) unsigned short lBl[64 * 40];
  const int nt = blockIdx.x, mt = blockIdx.y, b = blockIdx.z;
  const int m0 = mt * 64, n0 = nt * 64;
  const int tid = threadIdx.x;
  const int row = tid >> 2, seg = tid & 3;
  const int lane = tid & 63, wv = tid >> 6;
  const int koff = (lane >> 4) * 8;
  f32x4 res[4] = {};
  for (int slot = 0; slot < 2; slot++){
    const int pair = b * 2 + slot;
    const int e = sel_e[pair];
    const float wgt = sel_w[pair];
    const unsigned short* s2p = s2 + (size_t)pair * (M_ * HID_);
    const unsigned short* bhp = w2h + ((size_t)e * C_ + n0 + row) * HID_ + seg * 8;
    const unsigned short* blp = w2l + ((size_t)e * C_ + n0 + row) * HID_ + seg * 8;
    f32x4 acc[4] = {};
    for (int kk = 0; kk < HID_; kk += 32){
      int r = m0 + row;
      u16x8 av = {};
      if (r < M_) av = *(const u16x8*)(s2p + (size_t)r * HID_ + kk + seg * 8);
      *(u16x8*)(lA  + row * 40 + seg * 8) = av;
      *(u16x8*)(lBh + row * 40 + seg * 8) = *(const u16x8*)(bhp + kk);
      *(u16x8*)(lBl + row * 40 + seg * 8) = *(const u16x8*)(blp + kk);
      __syncthreads();
      bf16x8 a = *(const bf16x8*)(lA + (wv * 16 + (lane & 15)) * 40 + koff);
      #pragma unroll
      for (int cb = 0; cb < 4; cb++){
        bf16x8 bh = *(const bf16x8*)(lBh + (cb * 16 + (lane & 15)) * 40 + koff);
        bf16x8 bl = *(const bf16x8*)(lBl + (cb * 16 + (lane & 15)) * 40 + koff);
        acc[cb] = __builtin_amdgcn_mfma_f32_16x16x32_bf16(a, bh, acc[cb], 0, 0, 0);
        acc[cb] = __builtin_amdgcn_mfma_f32_16x16x32_bf16(a, bl, acc[cb], 0, 0, 0);
      }
      __syncthreads();
    }
    #pragma unroll
    for (int cb = 0; cb < 4; cb++){
      int col = n0 + cb * 16 + (lane & 15);
      int pi = e * C_ + col;
      float sc = bn2_g[pi] / sqrtf(bn2_v[pi] + EPS_);
      float mm = bn2_m[pi], bb = bn2_b[pi], cbias = fc2_b[pi];
      #pragma unroll
      for (int t = 0; t < 4; t++){
        float z = acc[cb][t] + cbias;
        float y = (z - mm) * sc + bb;
        res[cb][t] += wgt * y;
      }
    }
  }
  const int rbase = m0 + wv * 16 + ((lane >> 4) << 2);
  if (rbase < M_){
    const int hw = rbase >> 2;
    #pragma unroll
    for (int cb = 0; cb < 4; cb++){
      int col = n0 + cb * 16 + (lane & 15);
      #pragma unroll
      for (int t = 0; t < 4; t++){
        size_t oi = ((size_t)(t * B_ + b) * C_ + col) * HW_ + hw;
        out[oi] = x[oi] + res[cb][t];
      }
    }
  }
}

extern "C" void kernel_launch(void* const* d_in, const int* in_sizes, int n_in,
                              void* d_out, int out_size, void* d_ws, size_t ws_size,
                              hipStream_t stream){
  const float* x     = (const float*)d_in[0];
  const float* rw    = (const float*)d_in[1];
  const float* rb    = (const float*)d_in[2];
  const float* rg    = (const float*)d_in[3];
  const float* rbb   = (const float*)d_in[4];
  const float* rm    = (const float*)d_in[5];
  const float* rv    = (const float*)d_in[6];
  const float* fc1_w = (const float*)d_in[7];
  const float* fc1_b = (const float*)d_in[8];
  const float* bn1_g = (const float*)d_in[9];
  const float* bn1_b = (const float*)d_in[10];
  const float* bn1_m = (const float*)d_in[11];
  const float* bn1_v = (const float*)d_in[12];
  const float* fc2_w = (const float*)d_in[13];
  const float* fc2_b = (const float*)d_in[14];
  const float* bn2_g = (const float*)d_in[15];
  const float* bn2_b = (const float*)d_in[16];
  const float* bn2_m = (const float*)d_in[17];
  const float* bn2_v = (const float*)d_in[18];
  const float* taus  = (const float*)d_in[19];
  float* out = (float*)d_out;

  char* ws = (char*)d_ws;
  size_t off = 0;
  auto alloc = [&](size_t bytes) -> char* {
    char* p = ws + off;
    off = (off + bytes + 255) & ~(size_t)255;
    return p;
  };
  const int NW = E_ * HID_ * C_;                        // 2,097,152 per weight
  unsigned short* w1h = (unsigned short*)alloc((size_t)NW * 2);
  unsigned short* w1l = (unsigned short*)alloc((size_t)NW * 2);
  unsigned short* w2h = (unsigned short*)alloc((size_t)NW * 2);
  unsigned short* w2l = (unsigned short*)alloc((size_t)NW * 2);
  unsigned short* s1  = (unsigned short*)alloc((size_t)NPAIR_ * M_ * C_ * 2);    // 6.4 MB
  unsigned short* s2  = (unsigned short*)alloc((size_t)NPAIR_ * M_ * HID_ * 2);  // 25.7 MB
  float* xbar  = (float*)alloc(B_ * C_ * 4);
  int*   sel_e = (int*)alloc(NPAIR_ * 4);
  float* sel_w = (float*)alloc(NPAIR_ * 4);
  (void)ws_size; (void)in_sizes; (void)n_in; (void)out_size;

  wconv_kernel<<<(NW + 255) / 256, 256, 0, stream>>>(fc1_w, w1h, w1l, NW);
  wconv_kernel<<<(NW + 255) / 256, 256, 0, stream>>>(fc2_w, w2h, w2l, NW);
  xbar_kernel<<<B_ * C_, 64, 0, stream>>>(x, xbar);
  router_kernel<<<1, 64, 0, stream>>>(xbar, rw, rb, rg, rbb, rm, rv, sel_e, sel_w);
  lif1_kernel<<<dim3(HW_, NPAIR_), 256, 0, stream>>>(x, sel_e, taus, s1);
  g1_kernel<<<dim3(HID_ / 64, (M_ + 63) / 64, NPAIR_), 256, 0, stream>>>(
      s1, w1h, w1l, fc1_b, bn1_g, bn1_b, bn1_m, bn1_v, sel_e, taus, s2);
  g2_kernel<<<dim3(C_ / 64, (M_ + 63) / 64, B_), 256, 0, stream>>>(
      s2, w2h, w2l, fc2_b, bn2_g, bn2_b, bn2_m, bn2_v, sel_e, sel_w, x, out);
}